// Round 2
// baseline (2779.872 us; speedup 1.0000x reference)
//
#include <hip/hip_runtime.h>
#include <math.h>

#define DIM 768
#define NH 12
#define HD 64
#define HIDDEN 3072
#define BB 16
#define TT 577
#define BT (BB*TT)   // 9232

// ---------------- LayerNorm: one 256-thread block per row of 768 ----------------
__global__ __launch_bounds__(256) void ln_kernel(const float* __restrict__ x,
                                                 const float* __restrict__ w,
                                                 const float* __restrict__ b,
                                                 float* __restrict__ out) {
    int row = blockIdx.x;
    const float* xr = x + (size_t)row * DIM;
    float* outr = out + (size_t)row * DIM;
    int t = threadIdx.x;
    float v0 = xr[t], v1 = xr[t + 256], v2 = xr[t + 512];
    float s = v0 + v1 + v2;
    float sq = v0 * v0 + v1 * v1 + v2 * v2;
    __shared__ float red[8];
    int lane = t & 63, wid = t >> 6;
    #pragma unroll
    for (int off = 32; off; off >>= 1) {
        s  += __shfl_down(s, off);
        sq += __shfl_down(sq, off);
    }
    if (lane == 0) { red[wid] = s; red[4 + wid] = sq; }
    __syncthreads();
    if (t == 0) {
        float ts = red[0] + red[1] + red[2] + red[3];
        float tq = red[4] + red[5] + red[6] + red[7];
        float mu = ts * (1.0f / DIM);
        float var = tq * (1.0f / DIM) - mu * mu;
        red[0] = mu;
        red[1] = rsqrtf(var + 1e-6f);
    }
    __syncthreads();
    float mu = red[0], rstd = red[1];
    outr[t]       = (v0 - mu) * rstd * w[t]       + b[t];
    outr[t + 256] = (v1 - mu) * rstd * w[t + 256] + b[t + 256];
    outr[t + 512] = (v2 - mu) * rstd * w[t + 512] + b[t + 512];
}

// ---------------- fp32 tiled GEMM: C = A[M,K] @ W[K,N] + bias (+epilogue) -------
// EPI: 0 = none, 1 = exact GELU, 2 = + resid
template<int EPI>
__global__ __launch_bounds__(256) void gemm_kernel(const float* __restrict__ A,
                                                   const float* __restrict__ W,
                                                   const float* __restrict__ bias,
                                                   const float* __restrict__ resid,
                                                   float* __restrict__ C,
                                                   int M, int N, int K) {
    const int BM = 64, BN = 64, BK = 16;
    __shared__ __align__(16) float As[BK][BM];
    __shared__ __align__(16) float Bs[BK][BN];
    int bx = blockIdx.x, by = blockIdx.y;
    int tid = threadIdx.x;
    int tx = tid & 15, ty = tid >> 4;
    int row0 = by * BM, col0 = bx * BN;
    float acc[4][4] = {};
    int arow = tid >> 2;        // 0..63
    int acol = (tid & 3) * 4;   // 0,4,8,12
    int brow = tid >> 4;        // 0..15
    int bcol = (tid & 15) * 4;  // 0..60

    for (int k0 = 0; k0 < K; k0 += BK) {
        int ar = row0 + arow;
        float4 av = make_float4(0.f, 0.f, 0.f, 0.f);
        if (ar < M) av = *(const float4*)(A + (size_t)ar * K + k0 + acol);
        As[acol + 0][arow] = av.x;
        As[acol + 1][arow] = av.y;
        As[acol + 2][arow] = av.z;
        As[acol + 3][arow] = av.w;
        *(float4*)&Bs[brow][bcol] = *(const float4*)(W + (size_t)(k0 + brow) * N + col0 + bcol);
        __syncthreads();
        #pragma unroll
        for (int kk = 0; kk < BK; ++kk) {
            float a0 = As[kk][ty * 4 + 0], a1 = As[kk][ty * 4 + 1];
            float a2 = As[kk][ty * 4 + 2], a3 = As[kk][ty * 4 + 3];
            float b0 = Bs[kk][tx * 4 + 0], b1 = Bs[kk][tx * 4 + 1];
            float b2 = Bs[kk][tx * 4 + 2], b3 = Bs[kk][tx * 4 + 3];
            acc[0][0] += a0 * b0; acc[0][1] += a0 * b1; acc[0][2] += a0 * b2; acc[0][3] += a0 * b3;
            acc[1][0] += a1 * b0; acc[1][1] += a1 * b1; acc[1][2] += a1 * b2; acc[1][3] += a1 * b3;
            acc[2][0] += a2 * b0; acc[2][1] += a2 * b1; acc[2][2] += a2 * b2; acc[2][3] += a2 * b3;
            acc[3][0] += a3 * b0; acc[3][1] += a3 * b1; acc[3][2] += a3 * b2; acc[3][3] += a3 * b3;
        }
        __syncthreads();
    }
    #pragma unroll
    for (int i = 0; i < 4; ++i) {
        int r = row0 + ty * 4 + i;
        if (r >= M) continue;
        #pragma unroll
        for (int j = 0; j < 4; ++j) {
            int c = col0 + tx * 4 + j;
            float v = acc[i][j] + bias[c];
            if (EPI == 1) v = 0.5f * v * (1.0f + erff(v * 0.70710678118f));
            if (EPI == 2) v += resid[(size_t)r * N + c];
            C[(size_t)r * N + c] = v;
        }
    }
}

// ---------------- flash-style attention, fp32, one wave per 64 q-rows -----------
__global__ __launch_bounds__(64) void attn_kernel(const float* __restrict__ qkv,
                                                  float* __restrict__ wa) {
    int qt = blockIdx.x;   // 0..9
    int h  = blockIdx.y;   // 0..11
    int b  = blockIdx.z;   // 0..15
    int t = threadIdx.x;   // 0..63
    int r = qt * 64 + t;
    bool active = (r < TT);
    __shared__ __align__(16) float Ks[64][64];
    __shared__ __align__(16) float Vs[64][64];
    const float scale = 0.125f;  // 1/sqrt(64)

    float q[64];
    const float* qbase = qkv + (size_t)(b * TT + (active ? r : 0)) * 2304 + h * 64;
    #pragma unroll
    for (int d4 = 0; d4 < 16; ++d4) {
        float4 v = *(const float4*)(qbase + d4 * 4);
        q[d4 * 4 + 0] = v.x * scale; q[d4 * 4 + 1] = v.y * scale;
        q[d4 * 4 + 2] = v.z * scale; q[d4 * 4 + 3] = v.w * scale;
    }
    float o[64];
    #pragma unroll
    for (int d = 0; d < 64; ++d) o[d] = 0.f;
    float m = -1e30f, l = 0.f;

    for (int kt = 0; kt < TT; kt += 64) {
        int nk = min(64, TT - kt);
        #pragma unroll
        for (int it = 0; it < 16; ++it) {
            int idx = it * 64 + t;
            int row = idx >> 4;
            int c4 = idx & 15;
            int krow = kt + row;
            if (krow < TT) {
                const float* kb = qkv + (size_t)(b * TT + krow) * 2304 + 768 + h * 64;
                *(float4*)&Ks[row][c4 * 4] = *(const float4*)(kb + c4 * 4);
                *(float4*)&Vs[row][c4 * 4] = *(const float4*)(kb + 768 + c4 * 4);
            }
        }
        __syncthreads();
        if (active) {
            for (int j0 = 0; j0 < nk; j0 += 8) {
                float s[8];
                #pragma unroll
                for (int jj = 0; jj < 8; ++jj) {
                    int j = j0 + jj;
                    if (j < nk) {
                        float a0 = 0.f, a1 = 0.f, a2 = 0.f, a3 = 0.f;
                        #pragma unroll
                        for (int d4 = 0; d4 < 16; ++d4) {
                            float4 kv = *(const float4*)&Ks[j][d4 * 4];
                            a0 += q[d4 * 4 + 0] * kv.x;
                            a1 += q[d4 * 4 + 1] * kv.y;
                            a2 += q[d4 * 4 + 2] * kv.z;
                            a3 += q[d4 * 4 + 3] * kv.w;
                        }
                        s[jj] = (a0 + a1) + (a2 + a3);
                    } else {
                        s[jj] = -1e30f;
                    }
                }
                float mt = s[0];
                #pragma unroll
                for (int jj = 1; jj < 8; ++jj) mt = fmaxf(mt, s[jj]);
                if (mt > m) {  // defer-max: only rescale when running max grows
                    float corr = __expf(m - mt);
                    m = mt;
                    l *= corr;
                    #pragma unroll
                    for (int d = 0; d < 64; ++d) o[d] *= corr;
                }
                #pragma unroll
                for (int jj = 0; jj < 8; ++jj) {
                    float p = __expf(s[jj] - m);
                    l += p;
                    #pragma unroll
                    for (int d4 = 0; d4 < 16; ++d4) {
                        float4 vv = *(const float4*)&Vs[j0 + jj][d4 * 4];
                        o[d4 * 4 + 0] += p * vv.x;
                        o[d4 * 4 + 1] += p * vv.y;
                        o[d4 * 4 + 2] += p * vv.z;
                        o[d4 * 4 + 3] += p * vv.w;
                    }
                }
            }
        }
        __syncthreads();
    }
    if (active) {
        float inv = 1.0f / l;
        float* ob = wa + (size_t)(b * TT + r) * DIM + h * 64;
        #pragma unroll
        for (int d4 = 0; d4 < 16; ++d4) {
            float4 vv;
            vv.x = o[d4 * 4 + 0] * inv; vv.y = o[d4 * 4 + 1] * inv;
            vv.z = o[d4 * 4 + 2] * inv; vv.w = o[d4 * 4 + 3] * inv;
            *(float4*)(ob + d4 * 4) = vv;
        }
    }
}

// --------------------------------------------------------------------------------
extern "C" void kernel_launch(void* const* d_in, const int* in_sizes, int n_in,
                              void* d_out, int out_size, void* d_ws, size_t ws_size,
                              hipStream_t stream) {
    const float* x      = (const float*)d_in[0];
    const float* ln1_w  = (const float*)d_in[1];
    const float* ln1_b  = (const float*)d_in[2];
    const float* qkv_w  = (const float*)d_in[3];
    const float* qkv_b  = (const float*)d_in[4];
    const float* proj_w = (const float*)d_in[5];
    const float* proj_b = (const float*)d_in[6];
    const float* ln2_w  = (const float*)d_in[7];
    const float* ln2_b  = (const float*)d_in[8];
    const float* fc1_w  = (const float*)d_in[9];
    const float* fc1_b  = (const float*)d_in[10];
    const float* fc2_w  = (const float*)d_in[11];
    const float* fc2_b  = (const float*)d_in[12];
    float* out = (float*)d_out;

    float* ws  = (float*)d_ws;
    float* h   = ws;                           // BT*DIM   (shared with wa)
    float* qkv = h + (size_t)BT * DIM;         // BT*3*DIM
    float* x1  = qkv + (size_t)BT * 3 * DIM;   // BT*DIM
    float* hh  = x1 + (size_t)BT * DIM;        // BT*HIDDEN
    float* wa  = h;                            // reuse: h is dead after QKV GEMM

    dim3 blk(256);
    int mtiles = (BT + 63) / 64;

    // 1) h = LN1(x)
    ln_kernel<<<BT, blk, 0, stream>>>(x, ln1_w, ln1_b, h);
    // 2) qkv = h @ qkv_w + qkv_b
    gemm_kernel<0><<<dim3(3 * DIM / 64, mtiles), blk, 0, stream>>>(h, qkv_w, qkv_b, nullptr, qkv, BT, 3 * DIM, DIM);
    // 3) wa = attention(qkv)
    attn_kernel<<<dim3((TT + 63) / 64, NH, BB), dim3(64), 0, stream>>>(qkv, wa);
    // 4) x1 = x + wa @ proj_w + proj_b
    gemm_kernel<2><<<dim3(DIM / 64, mtiles), blk, 0, stream>>>(wa, proj_w, proj_b, x, x1, BT, DIM, DIM);
    // 5) h = LN2(x1)
    ln_kernel<<<BT, blk, 0, stream>>>(x1, ln2_w, ln2_b, h);
    // 6) hh = gelu(h @ fc1_w + fc1_b)
    gemm_kernel<1><<<dim3(HIDDEN / 64, mtiles), blk, 0, stream>>>(h, fc1_w, fc1_b, nullptr, hh, BT, HIDDEN, DIM);
    // 7) out = x1 + hh @ fc2_w + fc2_b
    gemm_kernel<2><<<dim3(DIM / 64, mtiles), blk, 0, stream>>>(hh, fc2_w, fc2_b, x1, out, BT, DIM, HIDDEN);
}

// Round 3
// 1600.877 us; speedup vs baseline: 1.7365x; 1.7365x over previous
//
#include <hip/hip_runtime.h>
#include <math.h>

#define DIM 768
#define NH 12
#define HIDDEN 3072
#define BB 16
#define TT 577
#define BT (BB*TT)      // 9232
#define MPAD 9344       // 73*128

typedef __attribute__((ext_vector_type(8))) short s16x8;
typedef __attribute__((ext_vector_type(8))) unsigned short u16x8;
typedef __attribute__((ext_vector_type(4))) float f32x4;

__device__ __forceinline__ unsigned short f2bf(float x) {
    unsigned u = __float_as_uint(x);
    u += 0x7fffu + ((u >> 16) & 1u);
    return (unsigned short)(u >> 16);
}
__device__ __forceinline__ float bf2f(unsigned short h) {
    return __uint_as_float(((unsigned)h) << 16);
}

// ---------------- LayerNorm -> split-bf16 planes (pre-swizzled) ----------------
__global__ __launch_bounds__(256) void ln_kernel(const float* __restrict__ x,
                                                 const float* __restrict__ w,
                                                 const float* __restrict__ b,
                                                 unsigned short* __restrict__ oh,
                                                 unsigned short* __restrict__ ol) {
    int row = blockIdx.x;
    const float* xr = x + (size_t)row * DIM;
    int t = threadIdx.x;
    float v0 = xr[t], v1 = xr[t + 256], v2 = xr[t + 512];
    float s = v0 + v1 + v2;
    float sq = v0 * v0 + v1 * v1 + v2 * v2;
    __shared__ float red[8];
    int lane = t & 63, wid = t >> 6;
    #pragma unroll
    for (int off = 32; off; off >>= 1) {
        s  += __shfl_down(s, off);
        sq += __shfl_down(sq, off);
    }
    if (lane == 0) { red[wid] = s; red[4 + wid] = sq; }
    __syncthreads();
    if (t == 0) {
        float ts = red[0] + red[1] + red[2] + red[3];
        float tq = red[4] + red[5] + red[6] + red[7];
        float mu = ts * (1.0f / DIM);
        float var = tq * (1.0f / DIM) - mu * mu;
        red[0] = mu;
        red[1] = rsqrtf(var + 1e-6f);
    }
    __syncthreads();
    float mu = red[0], rstd = red[1];
    int sw = (row & 7) << 3;
    size_t ro = (size_t)row * DIM;
    #pragma unroll
    for (int e = 0; e < 3; ++e) {
        int c = t + e * 256;
        float v = (e == 0 ? v0 : (e == 1 ? v1 : v2));
        float val = (v - mu) * rstd * w[c] + b[c];
        unsigned short hb = f2bf(val);
        unsigned short lb = f2bf(val - bf2f(hb));
        oh[ro + (c ^ sw)] = hb;
        ol[ro + (c ^ sw)] = lb;
    }
}

// -------- weight convert: fp32 [K][N] -> bf16 hi/lo planes [N][K], pre-swizzled --------
__global__ __launch_bounds__(256) void convert_wT(const float* __restrict__ src,
                                                  unsigned short* __restrict__ dh,
                                                  unsigned short* __restrict__ dl,
                                                  int K, int N) {
    int n = blockIdx.x * 64 + (threadIdx.x & 63);
    int k0 = blockIdx.y * 32 + (threadIdx.x >> 6) * 8;
    u16x8 h8, l8;
    #pragma unroll
    for (int j = 0; j < 8; ++j) {
        float v = src[(size_t)(k0 + j) * N + n];
        unsigned short hb = f2bf(v);
        h8[j] = hb;
        l8[j] = f2bf(v - bf2f(hb));
    }
    size_t off = (size_t)n * K + (k0 ^ ((n & 7) << 3));
    *(u16x8*)&dh[off] = h8;
    *(u16x8*)&dl[off] = l8;
}

// ---------------- split-bf16 MFMA GEMM: C = A @ W^T(+bias, +epi) ----------------
// A planes [Mpad][K], B planes [N][K], both pre-swizzled (k ^ ((row&7)<<3)).
// EPI: 0 = fp32 out, 1 = GELU -> bf16 planes out, 2 = +resid fp32 out
template<int EPI>
__global__ __launch_bounds__(256) void gemm_mfma(
    const unsigned short* __restrict__ Ah, const unsigned short* __restrict__ Al,
    const unsigned short* __restrict__ Bh, const unsigned short* __restrict__ Bl,
    const float* __restrict__ bias, const float* __restrict__ resid,
    float* __restrict__ C,
    unsigned short* __restrict__ Oh, unsigned short* __restrict__ Ol,
    int M, int N, int K) {
    __shared__ unsigned short lds[4][128][64];  // Ah, Al, Bh, Bl tiles: 64 KiB
    int tid = threadIdx.x;
    int wid = tid >> 6, lane = tid & 63;
    int m0 = blockIdx.y * 128, n0 = blockIdx.x * 128;
    int wr = wid >> 1, wc = wid & 1;

    // wave `wid` stages plane `wid`: 16 issues x 1KiB (64 lanes x 16B), linear dest
    const unsigned short* src = (wid == 0) ? Ah : ((wid == 1) ? Al : ((wid == 2) ? Bh : Bl));
    int srow0 = (wid < 2) ? m0 : n0;
    unsigned short* lbase = &lds[wid][0][0];
    const unsigned short* gbase = src + (size_t)(srow0 + (lane >> 3)) * K + (lane & 7) * 8;

    f32x4 acc[4][4];
    #pragma unroll
    for (int i = 0; i < 4; ++i)
        #pragma unroll
        for (int j = 0; j < 4; ++j) acc[i][j] = (f32x4)0.0f;

    for (int k0 = 0; k0 < K; k0 += 64) {
        #pragma unroll
        for (int i = 0; i < 16; ++i) {
            __builtin_amdgcn_global_load_lds(
                (const __attribute__((address_space(1))) void*)(gbase + (size_t)i * 8 * K + k0),
                (__attribute__((address_space(3))) void*)(lbase + i * 512),
                16, 0, 0);
        }
        __syncthreads();
        #pragma unroll
        for (int kk = 0; kk < 2; ++kk) {
            int so = (((kk * 4 + (lane >> 4)) ^ (lane & 7)) << 3);
            s16x8 ahf[4], alf[4], bhf[4], blf[4];
            #pragma unroll
            for (int m = 0; m < 4; ++m) {
                int r = wr * 64 + m * 16 + (lane & 15);
                ahf[m] = *(const s16x8*)&lds[0][r][so];
                alf[m] = *(const s16x8*)&lds[1][r][so];
            }
            #pragma unroll
            for (int n = 0; n < 4; ++n) {
                int r = wc * 64 + n * 16 + (lane & 15);
                bhf[n] = *(const s16x8*)&lds[2][r][so];
                blf[n] = *(const s16x8*)&lds[3][r][so];
            }
            #pragma unroll
            for (int m = 0; m < 4; ++m)
                #pragma unroll
                for (int n = 0; n < 4; ++n) {
                    acc[m][n] = __builtin_amdgcn_mfma_f32_16x16x32_bf16(ahf[m], bhf[n], acc[m][n], 0, 0, 0);
                    acc[m][n] = __builtin_amdgcn_mfma_f32_16x16x32_bf16(ahf[m], blf[n], acc[m][n], 0, 0, 0);
                    acc[m][n] = __builtin_amdgcn_mfma_f32_16x16x32_bf16(alf[m], bhf[n], acc[m][n], 0, 0, 0);
                }
        }
        __syncthreads();
    }

    // epilogue: C row = (lane>>4)*4 + reg, col = lane&15 (m89-verified layout)
    int rbase = m0 + wr * 64 + (lane >> 4) * 4;
    int cbase = n0 + wc * 64 + (lane & 15);
    #pragma unroll
    for (int mi = 0; mi < 4; ++mi) {
        #pragma unroll
        for (int ni = 0; ni < 4; ++ni) {
            int c = cbase + ni * 16;
            float bsv = bias[c];
            #pragma unroll
            for (int r4 = 0; r4 < 4; ++r4) {
                int r = rbase + mi * 16 + r4;
                if (r < M) {
                    float v = acc[mi][ni][r4] + bsv;
                    if (EPI == 1) {
                        v = 0.5f * v * (1.0f + erff(v * 0.70710678118f));
                        unsigned short hb = f2bf(v);
                        unsigned short lb = f2bf(v - bf2f(hb));
                        size_t o = (size_t)r * N + (c ^ ((r & 7) << 3));
                        Oh[o] = hb;
                        Ol[o] = lb;
                    } else {
                        if (EPI == 2) v += resid[(size_t)r * N + c];
                        C[(size_t)r * N + c] = v;
                    }
                }
            }
        }
    }
}

// ---------------- flash attention (fp32 in, split-bf16 planes out) ----------------
__global__ __launch_bounds__(64) void attn_kernel(const float* __restrict__ qkv,
                                                  unsigned short* __restrict__ wah,
                                                  unsigned short* __restrict__ wal) {
    int qt = blockIdx.x;
    int h  = blockIdx.y;
    int b  = blockIdx.z;
    int t = threadIdx.x;
    int r = qt * 64 + t;
    bool active = (r < TT);
    __shared__ __align__(16) float Ks[64][64];
    __shared__ __align__(16) float Vs[64][64];
    const float scale = 0.125f;

    float q[64];
    const float* qbase = qkv + (size_t)(b * TT + (active ? r : 0)) * 2304 + h * 64;
    #pragma unroll
    for (int d4 = 0; d4 < 16; ++d4) {
        float4 v = *(const float4*)(qbase + d4 * 4);
        q[d4 * 4 + 0] = v.x * scale; q[d4 * 4 + 1] = v.y * scale;
        q[d4 * 4 + 2] = v.z * scale; q[d4 * 4 + 3] = v.w * scale;
    }
    float o[64];
    #pragma unroll
    for (int d = 0; d < 64; ++d) o[d] = 0.f;
    float m = -1e30f, l = 0.f;

    for (int kt = 0; kt < TT; kt += 64) {
        int nk = min(64, TT - kt);
        #pragma unroll
        for (int it = 0; it < 16; ++it) {
            int idx = it * 64 + t;
            int row = idx >> 4;
            int c4 = idx & 15;
            int krow = kt + row;
            if (krow < TT) {
                const float* kb = qkv + (size_t)(b * TT + krow) * 2304 + 768 + h * 64;
                *(float4*)&Ks[row][c4 * 4] = *(const float4*)(kb + c4 * 4);
                *(float4*)&Vs[row][c4 * 4] = *(const float4*)(kb + 768 + c4 * 4);
            }
        }
        __syncthreads();
        if (active) {
            for (int j0 = 0; j0 < nk; j0 += 8) {
                float s[8];
                #pragma unroll
                for (int jj = 0; jj < 8; ++jj) {
                    int j = j0 + jj;
                    if (j < nk) {
                        float a0 = 0.f, a1 = 0.f, a2 = 0.f, a3 = 0.f;
                        #pragma unroll
                        for (int d4 = 0; d4 < 16; ++d4) {
                            float4 kv = *(const float4*)&Ks[j][d4 * 4];
                            a0 += q[d4 * 4 + 0] * kv.x;
                            a1 += q[d4 * 4 + 1] * kv.y;
                            a2 += q[d4 * 4 + 2] * kv.z;
                            a3 += q[d4 * 4 + 3] * kv.w;
                        }
                        s[jj] = (a0 + a1) + (a2 + a3);
                    } else {
                        s[jj] = -1e30f;
                    }
                }
                float mt = s[0];
                #pragma unroll
                for (int jj = 1; jj < 8; ++jj) mt = fmaxf(mt, s[jj]);
                if (mt > m) {
                    float corr = __expf(m - mt);
                    m = mt;
                    l *= corr;
                    #pragma unroll
                    for (int d = 0; d < 64; ++d) o[d] *= corr;
                }
                #pragma unroll
                for (int jj = 0; jj < 8; ++jj) {
                    float p = __expf(s[jj] - m);
                    l += p;
                    #pragma unroll
                    for (int d4 = 0; d4 < 16; ++d4) {
                        float4 vv = *(const float4*)&Vs[j0 + jj][d4 * 4];
                        o[d4 * 4 + 0] += p * vv.x;
                        o[d4 * 4 + 1] += p * vv.y;
                        o[d4 * 4 + 2] += p * vv.z;
                        o[d4 * 4 + 3] += p * vv.w;
                    }
                }
            }
        }
        __syncthreads();
    }
    if (active) {
        float inv = 1.0f / l;
        size_t R = (size_t)b * TT + r;
        int sw = ((int)(R & 7)) << 3;
        size_t ro = R * DIM;
        #pragma unroll
        for (int g = 0; g < 8; ++g) {
            u16x8 h8, l8;
            #pragma unroll
            for (int j = 0; j < 8; ++j) {
                float v = o[g * 8 + j] * inv;
                unsigned short hb = f2bf(v);
                h8[j] = hb;
                l8[j] = f2bf(v - bf2f(hb));
            }
            int koff = h * 64 + ((g * 8) ^ sw);
            *(u16x8*)&wah[ro + koff] = h8;
            *(u16x8*)&wal[ro + koff] = l8;
        }
    }
}

// --------------------------------------------------------------------------------
extern "C" void kernel_launch(void* const* d_in, const int* in_sizes, int n_in,
                              void* d_out, int out_size, void* d_ws, size_t ws_size,
                              hipStream_t stream) {
    const float* x      = (const float*)d_in[0];
    const float* ln1_w  = (const float*)d_in[1];
    const float* ln1_b  = (const float*)d_in[2];
    const float* qkv_w  = (const float*)d_in[3];
    const float* qkv_b  = (const float*)d_in[4];
    const float* proj_w = (const float*)d_in[5];
    const float* proj_b = (const float*)d_in[6];
    const float* ln2_w  = (const float*)d_in[7];
    const float* ln2_b  = (const float*)d_in[8];
    const float* fc1_w  = (const float*)d_in[9];
    const float* fc1_b  = (const float*)d_in[10];
    const float* fc2_w  = (const float*)d_in[11];
    const float* fc2_b  = (const float*)d_in[12];
    float* out = (float*)d_out;

    const size_t P768  = (size_t)MPAD * 768;
    const size_t P3072 = (size_t)MPAD * 3072;
    char* wsb = (char*)d_ws;
    auto alloc = [&](size_t bytes) -> char* {
        char* p = wsb;
        wsb += (bytes + 255) & ~(size_t)255;
        return p;
    };
    unsigned short* h_hi  = (unsigned short*)alloc(P768 * 2);
    unsigned short* h_lo  = (unsigned short*)alloc(P768 * 2);
    unsigned short* wa_hi = (unsigned short*)alloc(P768 * 2);
    unsigned short* wa_lo = (unsigned short*)alloc(P768 * 2);
    float* x1 = (float*)alloc((size_t)BT * 768 * 4);
    unsigned short* qkvT_h = (unsigned short*)alloc((size_t)2304 * 768 * 2);
    unsigned short* qkvT_l = (unsigned short*)alloc((size_t)2304 * 768 * 2);
    unsigned short* projT_h = (unsigned short*)alloc((size_t)768 * 768 * 2);
    unsigned short* projT_l = (unsigned short*)alloc((size_t)768 * 768 * 2);
    unsigned short* fc1T_h = (unsigned short*)alloc((size_t)3072 * 768 * 2);
    unsigned short* fc1T_l = (unsigned short*)alloc((size_t)3072 * 768 * 2);
    unsigned short* fc2T_h = (unsigned short*)alloc((size_t)768 * 3072 * 2);
    unsigned short* fc2T_l = (unsigned short*)alloc((size_t)768 * 3072 * 2);
    // union region: qkv fp32 (85MB) / hh planes (115MB) — sequential lifetimes
    char* ubase = alloc(2 * P3072 * 2);
    float* qkv = (float*)ubase;
    unsigned short* hh_hi = (unsigned short*)ubase;
    unsigned short* hh_lo = hh_hi + P3072;

    dim3 blk(256);
    int mt = (BT + 127) / 128;  // 73

    // weight conversion (transpose + split + swizzle)
    convert_wT<<<dim3(2304 / 64, 768 / 32), blk, 0, stream>>>(qkv_w, qkvT_h, qkvT_l, 768, 2304);
    convert_wT<<<dim3(768 / 64, 768 / 32), blk, 0, stream>>>(proj_w, projT_h, projT_l, 768, 768);
    convert_wT<<<dim3(3072 / 64, 768 / 32), blk, 0, stream>>>(fc1_w, fc1T_h, fc1T_l, 768, 3072);
    convert_wT<<<dim3(768 / 64, 3072 / 32), blk, 0, stream>>>(fc2_w, fc2T_h, fc2T_l, 3072, 768);

    // 1) h = LN1(x)  -> planes
    ln_kernel<<<BT, blk, 0, stream>>>(x, ln1_w, ln1_b, h_hi, h_lo);
    // 2) qkv = h @ qkv_w + qkv_b   (fp32 out)
    gemm_mfma<0><<<dim3(2304 / 128, mt), blk, 0, stream>>>(h_hi, h_lo, qkvT_h, qkvT_l, qkv_b,
                                                           nullptr, qkv, nullptr, nullptr, BT, 2304, 768);
    // 3) wa = attention(qkv) -> planes
    attn_kernel<<<dim3((TT + 63) / 64, NH, BB), dim3(64), 0, stream>>>(qkv, wa_hi, wa_lo);
    // 4) x1 = x + wa @ proj_w + proj_b
    gemm_mfma<2><<<dim3(768 / 128, mt), blk, 0, stream>>>(wa_hi, wa_lo, projT_h, projT_l, proj_b,
                                                          x, x1, nullptr, nullptr, BT, 768, 768);
    // 5) h = LN2(x1) -> planes
    ln_kernel<<<BT, blk, 0, stream>>>(x1, ln2_w, ln2_b, h_hi, h_lo);
    // 6) hh = gelu(h @ fc1_w + fc1_b) -> planes
    gemm_mfma<1><<<dim3(3072 / 128, mt), blk, 0, stream>>>(h_hi, h_lo, fc1T_h, fc1T_l, fc1_b,
                                                           nullptr, nullptr, hh_hi, hh_lo, BT, 3072, 768);
    // 7) out = x1 + hh @ fc2_w + fc2_b
    gemm_mfma<2><<<dim3(768 / 128, mt), blk, 0, stream>>>(hh_hi, hh_lo, fc2T_h, fc2T_l, fc2_b,
                                                          x1, out, nullptr, nullptr, BT, 768, 3072);
}

// Round 4
// 780.366 us; speedup vs baseline: 3.5623x; 2.0514x over previous
//
#include <hip/hip_runtime.h>
#include <math.h>

#define DIM 768
#define NH 12
#define HIDDEN 3072
#define BB 16
#define TT 577
#define TPAD 640
#define BT (BB*TT)      // 9232
#define MPAD 9344       // 73*128

typedef __attribute__((ext_vector_type(8))) short s16x8;
typedef __attribute__((ext_vector_type(8))) unsigned short u16x8;
typedef __attribute__((ext_vector_type(4))) float f32x4;

__device__ __forceinline__ unsigned short f2bf(float x) {
    unsigned u = __float_as_uint(x);
    u += 0x7fffu + ((u >> 16) & 1u);
    return (unsigned short)(u >> 16);
}
__device__ __forceinline__ float bf2f(unsigned short h) {
    return __uint_as_float(((unsigned)h) << 16);
}

// ---------------- LayerNorm -> split-bf16 planes (pre-swizzled) ----------------
__global__ __launch_bounds__(256) void ln_kernel(const float* __restrict__ x,
                                                 const float* __restrict__ w,
                                                 const float* __restrict__ b,
                                                 unsigned short* __restrict__ oh,
                                                 unsigned short* __restrict__ ol) {
    int row = blockIdx.x;
    const float* xr = x + (size_t)row * DIM;
    int t = threadIdx.x;
    float v0 = xr[t], v1 = xr[t + 256], v2 = xr[t + 512];
    float s = v0 + v1 + v2;
    float sq = v0 * v0 + v1 * v1 + v2 * v2;
    __shared__ float red[8];
    int lane = t & 63, wid = t >> 6;
    #pragma unroll
    for (int off = 32; off; off >>= 1) {
        s  += __shfl_down(s, off);
        sq += __shfl_down(sq, off);
    }
    if (lane == 0) { red[wid] = s; red[4 + wid] = sq; }
    __syncthreads();
    if (t == 0) {
        float ts = red[0] + red[1] + red[2] + red[3];
        float tq = red[4] + red[5] + red[6] + red[7];
        float mu = ts * (1.0f / DIM);
        float var = tq * (1.0f / DIM) - mu * mu;
        red[0] = mu;
        red[1] = rsqrtf(var + 1e-6f);
    }
    __syncthreads();
    float mu = red[0], rstd = red[1];
    int sw = (row & 7) << 3;
    size_t ro = (size_t)row * DIM;
    #pragma unroll
    for (int e = 0; e < 3; ++e) {
        int c = t + e * 256;
        float v = (e == 0 ? v0 : (e == 1 ? v1 : v2));
        float val = (v - mu) * rstd * w[c] + b[c];
        unsigned short hb = f2bf(val);
        unsigned short lb = f2bf(val - bf2f(hb));
        oh[ro + (c ^ sw)] = hb;
        ol[ro + (c ^ sw)] = lb;
    }
}

// -------- weight convert: fp32 [K][N] -> bf16 hi/lo planes [N][K], pre-swizzled --------
__global__ __launch_bounds__(256) void convert_wT(const float* __restrict__ src,
                                                  unsigned short* __restrict__ dh,
                                                  unsigned short* __restrict__ dl,
                                                  int K, int N) {
    int n = blockIdx.x * 64 + (threadIdx.x & 63);
    int k0 = blockIdx.y * 32 + (threadIdx.x >> 6) * 8;
    u16x8 h8, l8;
    #pragma unroll
    for (int j = 0; j < 8; ++j) {
        float v = src[(size_t)(k0 + j) * N + n];
        unsigned short hb = f2bf(v);
        h8[j] = hb;
        l8[j] = f2bf(v - bf2f(hb));
    }
    size_t off = (size_t)n * K + (k0 ^ ((n & 7) << 3));
    *(u16x8*)&dh[off] = h8;
    *(u16x8*)&dl[off] = l8;
}

// ---------------- split-bf16 MFMA GEMM: C = A @ W^T(+bias, +epi) ----------------
// A planes [Mpad][K], B planes [N][K], both pre-swizzled (k ^ ((row&7)<<3)).
// EPI: 1 = GELU -> bf16 planes out, 2 = +resid fp32 out, 3 = QKV -> attention planes
template<int EPI>
__global__ __launch_bounds__(256) void gemm_mfma(
    const unsigned short* __restrict__ Ah, const unsigned short* __restrict__ Al,
    const unsigned short* __restrict__ Bh, const unsigned short* __restrict__ Bl,
    const float* __restrict__ bias, const float* __restrict__ resid,
    float* __restrict__ C,
    unsigned short* __restrict__ Oh, unsigned short* __restrict__ Ol,
    unsigned short* __restrict__ pQh, unsigned short* __restrict__ pQl,
    unsigned short* __restrict__ pKh, unsigned short* __restrict__ pKl,
    unsigned short* __restrict__ pVTh, unsigned short* __restrict__ pVTl,
    int M, int N, int K) {
    __shared__ unsigned short lds[4][128][64];  // Ah, Al, Bh, Bl tiles: 64 KiB
    int tid = threadIdx.x;
    int wid = tid >> 6, lane = tid & 63;
    int m0 = blockIdx.y * 128, n0 = blockIdx.x * 128;
    int wr = wid >> 1, wc = wid & 1;

    const unsigned short* src = (wid == 0) ? Ah : ((wid == 1) ? Al : ((wid == 2) ? Bh : Bl));
    int srow0 = (wid < 2) ? m0 : n0;
    unsigned short* lbase = &lds[wid][0][0];
    const unsigned short* gbase = src + (size_t)(srow0 + (lane >> 3)) * K + (lane & 7) * 8;

    f32x4 acc[4][4];
    #pragma unroll
    for (int i = 0; i < 4; ++i)
        #pragma unroll
        for (int j = 0; j < 4; ++j) acc[i][j] = (f32x4)0.0f;

    for (int k0 = 0; k0 < K; k0 += 64) {
        #pragma unroll
        for (int i = 0; i < 16; ++i) {
            __builtin_amdgcn_global_load_lds(
                (const __attribute__((address_space(1))) void*)(gbase + (size_t)i * 8 * K + k0),
                (__attribute__((address_space(3))) void*)(lbase + i * 512),
                16, 0, 0);
        }
        __syncthreads();
        #pragma unroll
        for (int kk = 0; kk < 2; ++kk) {
            int so = (((kk * 4 + (lane >> 4)) ^ (lane & 7)) << 3);
            s16x8 ahf[4], alf[4], bhf[4], blf[4];
            #pragma unroll
            for (int m = 0; m < 4; ++m) {
                int r = wr * 64 + m * 16 + (lane & 15);
                ahf[m] = *(const s16x8*)&lds[0][r][so];
                alf[m] = *(const s16x8*)&lds[1][r][so];
            }
            #pragma unroll
            for (int n = 0; n < 4; ++n) {
                int r = wc * 64 + n * 16 + (lane & 15);
                bhf[n] = *(const s16x8*)&lds[2][r][so];
                blf[n] = *(const s16x8*)&lds[3][r][so];
            }
            #pragma unroll
            for (int m = 0; m < 4; ++m)
                #pragma unroll
                for (int n = 0; n < 4; ++n) {
                    acc[m][n] = __builtin_amdgcn_mfma_f32_16x16x32_bf16(ahf[m], bhf[n], acc[m][n], 0, 0, 0);
                    acc[m][n] = __builtin_amdgcn_mfma_f32_16x16x32_bf16(ahf[m], blf[n], acc[m][n], 0, 0, 0);
                    acc[m][n] = __builtin_amdgcn_mfma_f32_16x16x32_bf16(alf[m], bhf[n], acc[m][n], 0, 0, 0);
                }
        }
        __syncthreads();
    }

    // epilogue: C row = (lane>>4)*4 + reg, col = lane&15
    int rbase = m0 + wr * 64 + (lane >> 4) * 4;
    int cbase = n0 + wc * 64 + (lane & 15);
    #pragma unroll
    for (int mi = 0; mi < 4; ++mi) {
        #pragma unroll
        for (int ni = 0; ni < 4; ++ni) {
            int c = cbase + ni * 16;
            float bsv = bias[c];
            #pragma unroll
            for (int r4 = 0; r4 < 4; ++r4) {
                int r = rbase + mi * 16 + r4;
                if (r >= M) continue;
                float v = acc[mi][ni][r4] + bsv;
                if (EPI == 1) {
                    v = 0.5f * v * (1.0f + erff(v * 0.70710678118f));
                    unsigned short hb = f2bf(v);
                    unsigned short lb = f2bf(v - bf2f(hb));
                    size_t o = (size_t)r * N + (c ^ ((r & 7) << 3));
                    Oh[o] = hb;
                    Ol[o] = lb;
                } else if (EPI == 2) {
                    v += resid[(size_t)r * N + c];
                    C[(size_t)r * N + c] = v;
                } else {  // EPI == 3: scatter to attention planes
                    int b_ = r / TT, t_ = r - b_ * TT;
                    int which = c / DIM, cc = c - which * DIM;
                    int head = cc >> 6, d = cc & 63;
                    size_t bh = (size_t)b_ * NH + head;
                    if (which == 0) {
                        v *= 0.125f;  // pre-apply 1/sqrt(64)
                        unsigned short hb = f2bf(v);
                        size_t o = (bh * TPAD + t_) * 64 + d;
                        pQh[o] = hb;
                        pQl[o] = f2bf(v - bf2f(hb));
                    } else if (which == 1) {
                        unsigned short hb = f2bf(v);
                        size_t o = (bh * TPAD + t_) * 64 + (d ^ ((t_ & 7) << 3));
                        pKh[o] = hb;
                        pKl[o] = f2bf(v - bf2f(hb));
                    } else {
                        unsigned short hb = f2bf(v);
                        size_t o = (bh * 64 + d) * TPAD + ((t_ & ~63) | ((t_ & 63) ^ ((d & 7) << 3)));
                        pVTh[o] = hb;
                        pVTl[o] = f2bf(v - bf2f(hb));
                    }
                }
            }
        }
    }
}

// ---------------- MFMA flash attention: 4 waves x 16 q-rows, KBLK=64 ----------------
// S = Qh*Kh + Qh*Kl + Ql*Kh (fp32-accurate logits); O += P*(Vh + Vl), P single bf16.
__global__ __launch_bounds__(256) void attn_mfma(
    const unsigned short* __restrict__ Qh, const unsigned short* __restrict__ Ql,
    const unsigned short* __restrict__ Kh, const unsigned short* __restrict__ Kl,
    const unsigned short* __restrict__ VTh, const unsigned short* __restrict__ VTl,
    unsigned short* __restrict__ wah, unsigned short* __restrict__ wal) {
    __shared__ unsigned short lds[20480];  // Kh,Kl,VTh,VTl [64][64] + P [4][16][64] = 40 KiB
    int tid = threadIdx.x, wid = tid >> 6, lane = tid & 63;
    int qt = blockIdx.x, h = blockIdx.y, b = blockIdx.z;
    size_t bh = (size_t)b * NH + h;

    // Q fragments (held in registers all kernel): A-frag row = lane&15, k-chunk = (lane>>4)*8
    int qrow = qt * 64 + wid * 16 + (lane & 15);
    const unsigned short* qb_h = Qh + (bh * TPAD + qrow) * 64 + (lane >> 4) * 8;
    const unsigned short* qb_l = Ql + (bh * TPAD + qrow) * 64 + (lane >> 4) * 8;
    s16x8 qfh[2], qfl[2];
    qfh[0] = *(const s16x8*)qb_h;        qfh[1] = *(const s16x8*)(qb_h + 32);
    qfl[0] = *(const s16x8*)qb_l;        qfl[1] = *(const s16x8*)(qb_l + 32);

    f32x4 oacc[4];
    #pragma unroll
    for (int dt = 0; dt < 4; ++dt) oacc[dt] = (f32x4)0.0f;
    float m[4] = {-1e30f, -1e30f, -1e30f, -1e30f};
    float lsum[4] = {0.f, 0.f, 0.f, 0.f};

    unsigned short* pbase = &lds[16384 + wid * 1024];

    for (int kt0 = 0; kt0 < TT; kt0 += 64) {
        // stage: wave `wid` stages plane `wid` (8 issues x 1 KiB, linear LDS dest)
        unsigned short* dst = &lds[wid * 4096];
        const unsigned short* gsrc;
        int istride;
        if (wid < 2) {
            const unsigned short* p = (wid == 0) ? Kh : Kl;
            gsrc = p + (bh * TPAD + kt0 + (lane >> 3)) * 64 + (lane & 7) * 8;
            istride = 8 * 64;
        } else {
            const unsigned short* p = (wid == 2) ? VTh : VTl;
            gsrc = p + (bh * 64 + (lane >> 3)) * TPAD + kt0 + (lane & 7) * 8;
            istride = 8 * TPAD;
        }
        #pragma unroll
        for (int i = 0; i < 8; ++i) {
            __builtin_amdgcn_global_load_lds(
                (const __attribute__((address_space(1))) void*)(gsrc + (size_t)i * istride),
                (__attribute__((address_space(3))) void*)(dst + i * 512),
                16, 0, 0);
        }
        __syncthreads();

        // ---- QK^T: S[16q][64k], 3-pass split ----
        f32x4 sacc[4];
        #pragma unroll
        for (int kt = 0; kt < 4; ++kt) sacc[kt] = (f32x4)0.0f;
        #pragma unroll
        for (int dstep = 0; dstep < 2; ++dstep) {
            #pragma unroll
            for (int kt = 0; kt < 4; ++kt) {
                int krow = kt * 16 + (lane & 15);
                int ko = (((dstep * 4 + (lane >> 4)) ^ (krow & 7)) << 3);
                s16x8 kbh = *(const s16x8*)&lds[0 * 4096 + krow * 64 + ko];
                s16x8 kbl = *(const s16x8*)&lds[1 * 4096 + krow * 64 + ko];
                sacc[kt] = __builtin_amdgcn_mfma_f32_16x16x32_bf16(qfh[dstep], kbh, sacc[kt], 0, 0, 0);
                sacc[kt] = __builtin_amdgcn_mfma_f32_16x16x32_bf16(qfh[dstep], kbl, sacc[kt], 0, 0, 0);
                sacc[kt] = __builtin_amdgcn_mfma_f32_16x16x32_bf16(qfl[dstep], kbh, sacc[kt], 0, 0, 0);
            }
        }
        // mask pad k-cols
        #pragma unroll
        for (int kt = 0; kt < 4; ++kt) {
            int kcol = kt0 + kt * 16 + (lane & 15);
            if (kcol >= TT) {
                #pragma unroll
                for (int r = 0; r < 4; ++r) sacc[kt][r] = -1e30f;
            }
        }
        // ---- online softmax (row r lives in lanes sharing lane>>4; cols across lane&15 x 4 kt) ----
        float mt[4];
        #pragma unroll
        for (int r = 0; r < 4; ++r)
            mt[r] = fmaxf(fmaxf(sacc[0][r], sacc[1][r]), fmaxf(sacc[2][r], sacc[3][r]));
        #pragma unroll
        for (int off = 1; off <= 8; off <<= 1) {
            #pragma unroll
            for (int r = 0; r < 4; ++r) mt[r] = fmaxf(mt[r], __shfl_xor(mt[r], off));
        }
        float corr[4];
        #pragma unroll
        for (int r = 0; r < 4; ++r) {
            float nm = fmaxf(m[r], mt[r]);
            corr[r] = __expf(m[r] - nm);
            m[r] = nm;
        }
        float rowsum[4] = {0.f, 0.f, 0.f, 0.f};
        #pragma unroll
        for (int kt = 0; kt < 4; ++kt) {
            #pragma unroll
            for (int r = 0; r < 4; ++r) {
                float p = __expf(sacc[kt][r] - m[r]);
                rowsum[r] += p;
                int q = (lane >> 4) * 4 + r;
                int kcol = kt * 16 + (lane & 15);
                pbase[q * 64 + (kcol ^ ((q & 7) << 3))] = f2bf(p);
            }
        }
        #pragma unroll
        for (int off = 1; off <= 8; off <<= 1) {
            #pragma unroll
            for (int r = 0; r < 4; ++r) rowsum[r] += __shfl_xor(rowsum[r], off);
        }
        #pragma unroll
        for (int r = 0; r < 4; ++r) {
            lsum[r] = lsum[r] * corr[r] + rowsum[r];
            #pragma unroll
            for (int dt = 0; dt < 4; ++dt) oacc[dt][r] *= corr[r];
        }
        // ---- PV: O[16q][64d] += P * (Vh + Vl) ----
        #pragma unroll
        for (int kc = 0; kc < 2; ++kc) {
            int q = lane & 15;
            int pko = (((kc * 4 + (lane >> 4)) ^ (q & 7)) << 3);
            s16x8 pa = *(const s16x8*)&pbase[q * 64 + pko];
            #pragma unroll
            for (int dt = 0; dt < 4; ++dt) {
                int drow = dt * 16 + (lane & 15);
                int vo = (((kc * 4 + (lane >> 4)) ^ (drow & 7)) << 3);
                s16x8 vh = *(const s16x8*)&lds[2 * 4096 + drow * 64 + vo];
                s16x8 vl = *(const s16x8*)&lds[3 * 4096 + drow * 64 + vo];
                oacc[dt] = __builtin_amdgcn_mfma_f32_16x16x32_bf16(pa, vh, oacc[dt], 0, 0, 0);
                oacc[dt] = __builtin_amdgcn_mfma_f32_16x16x32_bf16(pa, vl, oacc[dt], 0, 0, 0);
            }
        }
        __syncthreads();
    }

    // ---- epilogue: O row = (lane>>4)*4 + r, col d = dt*16 + (lane&15) ----
    #pragma unroll
    for (int r = 0; r < 4; ++r) {
        int t = qt * 64 + wid * 16 + (lane >> 4) * 4 + r;
        if (t >= TT) continue;
        float inv = 1.0f / lsum[r];
        size_t row = (size_t)b * TT + t;
        int sw = (int)(row & 7) << 3;
        size_t ro = row * DIM;
        #pragma unroll
        for (int dt = 0; dt < 4; ++dt) {
            int c = h * 64 + dt * 16 + (lane & 15);
            float v = oacc[dt][r] * inv;
            unsigned short hb = f2bf(v);
            wah[ro + (c ^ sw)] = hb;
            wal[ro + (c ^ sw)] = f2bf(v - bf2f(hb));
        }
    }
}

// --------------------------------------------------------------------------------
extern "C" void kernel_launch(void* const* d_in, const int* in_sizes, int n_in,
                              void* d_out, int out_size, void* d_ws, size_t ws_size,
                              hipStream_t stream) {
    const float* x      = (const float*)d_in[0];
    const float* ln1_w  = (const float*)d_in[1];
    const float* ln1_b  = (const float*)d_in[2];
    const float* qkv_w  = (const float*)d_in[3];
    const float* qkv_b  = (const float*)d_in[4];
    const float* proj_w = (const float*)d_in[5];
    const float* proj_b = (const float*)d_in[6];
    const float* ln2_w  = (const float*)d_in[7];
    const float* ln2_b  = (const float*)d_in[8];
    const float* fc1_w  = (const float*)d_in[9];
    const float* fc1_b  = (const float*)d_in[10];
    const float* fc2_w  = (const float*)d_in[11];
    const float* fc2_b  = (const float*)d_in[12];
    float* out = (float*)d_out;

    const size_t P768  = (size_t)MPAD * 768;
    const size_t P3072 = (size_t)MPAD * 3072;
    const size_t PQKV  = (size_t)BB * NH * TPAD * 64;  // one attention plane
    char* wsb = (char*)d_ws;
    auto alloc = [&](size_t bytes) -> char* {
        char* p = wsb;
        wsb += (bytes + 255) & ~(size_t)255;
        return p;
    };
    unsigned short* h_hi  = (unsigned short*)alloc(P768 * 2);
    unsigned short* h_lo  = (unsigned short*)alloc(P768 * 2);
    unsigned short* wa_hi = (unsigned short*)alloc(P768 * 2);
    unsigned short* wa_lo = (unsigned short*)alloc(P768 * 2);
    float* x1 = (float*)alloc((size_t)BT * 768 * 4);
    unsigned short* qkvT_h = (unsigned short*)alloc((size_t)2304 * 768 * 2);
    unsigned short* qkvT_l = (unsigned short*)alloc((size_t)2304 * 768 * 2);
    unsigned short* projT_h = (unsigned short*)alloc((size_t)768 * 768 * 2);
    unsigned short* projT_l = (unsigned short*)alloc((size_t)768 * 768 * 2);
    unsigned short* fc1T_h = (unsigned short*)alloc((size_t)3072 * 768 * 2);
    unsigned short* fc1T_l = (unsigned short*)alloc((size_t)3072 * 768 * 2);
    unsigned short* fc2T_h = (unsigned short*)alloc((size_t)768 * 3072 * 2);
    unsigned short* fc2T_l = (unsigned short*)alloc((size_t)768 * 3072 * 2);
    // union region: {Q,K,VT hi/lo planes: 6*PQKV} vs {hh planes: 2*P3072} — disjoint lifetimes
    char* ubase = alloc(2 * P3072 * 2);
    unsigned short* pQh  = (unsigned short*)ubase;
    unsigned short* pQl  = pQh + PQKV;
    unsigned short* pKh  = pQl + PQKV;
    unsigned short* pKl  = pKh + PQKV;
    unsigned short* pVTh = pKl + PQKV;
    unsigned short* pVTl = pVTh + PQKV;
    unsigned short* hh_hi = (unsigned short*)ubase;
    unsigned short* hh_lo = hh_hi + P3072;

    dim3 blk(256);
    int mt = (BT + 127) / 128;  // 73

    convert_wT<<<dim3(2304 / 64, 768 / 32), blk, 0, stream>>>(qkv_w, qkvT_h, qkvT_l, 768, 2304);
    convert_wT<<<dim3(768 / 64, 768 / 32), blk, 0, stream>>>(proj_w, projT_h, projT_l, 768, 768);
    convert_wT<<<dim3(3072 / 64, 768 / 32), blk, 0, stream>>>(fc1_w, fc1T_h, fc1T_l, 768, 3072);
    convert_wT<<<dim3(768 / 64, 3072 / 32), blk, 0, stream>>>(fc2_w, fc2T_h, fc2T_l, 3072, 768);

    // 1) h = LN1(x)
    ln_kernel<<<BT, blk, 0, stream>>>(x, ln1_w, ln1_b, h_hi, h_lo);
    // 2) qkv GEMM -> attention planes (Q scaled, K swizzled, V transposed)
    gemm_mfma<3><<<dim3(2304 / 128, mt), blk, 0, stream>>>(h_hi, h_lo, qkvT_h, qkvT_l, qkv_b,
        nullptr, nullptr, nullptr, nullptr, pQh, pQl, pKh, pKl, pVTh, pVTl, BT, 2304, 768);
    // 3) wa = attention -> split planes
    attn_mfma<<<dim3((TT + 63) / 64, NH, BB), blk, 0, stream>>>(pQh, pQl, pKh, pKl, pVTh, pVTl, wa_hi, wa_lo);
    // 4) x1 = x + wa @ proj_w + proj_b
    gemm_mfma<2><<<dim3(768 / 128, mt), blk, 0, stream>>>(wa_hi, wa_lo, projT_h, projT_l, proj_b,
        x, x1, nullptr, nullptr, nullptr, nullptr, nullptr, nullptr, nullptr, nullptr, BT, 768, 768);
    // 5) h = LN2(x1)
    ln_kernel<<<BT, blk, 0, stream>>>(x1, ln2_w, ln2_b, h_hi, h_lo);
    // 6) hh = gelu(h @ fc1_w + fc1_b) -> planes
    gemm_mfma<1><<<dim3(3072 / 128, mt), blk, 0, stream>>>(h_hi, h_lo, fc1T_h, fc1T_l, fc1_b,
        nullptr, nullptr, hh_hi, hh_lo, nullptr, nullptr, nullptr, nullptr, nullptr, nullptr, BT, 3072, 768);
    // 7) out = x1 + hh @ fc2_w + fc2_b
    gemm_mfma<2><<<dim3(768 / 128, mt), blk, 0, stream>>>(hh_hi, hh_lo, fc2T_h, fc2T_l, fc2_b,
        x1, out, nullptr, nullptr, nullptr, nullptr, nullptr, nullptr, nullptr, nullptr, BT, 768, 3072);
}

// Round 5
// 523.958 us; speedup vs baseline: 5.3055x; 1.4894x over previous
//
#include <hip/hip_runtime.h>
#include <math.h>

#define DIM 768
#define NH 12
#define HIDDEN 3072
#define BB 16
#define TT 577
#define TPAD 640
#define BT (BB*TT)      // 9232
#define MPAD 9344       // 73*128

typedef _Float16 f16x8 __attribute__((ext_vector_type(8)));
typedef __attribute__((ext_vector_type(4))) float f32x4;

// ---------------- LayerNorm -> fp16 plane (pre-swizzled) ----------------
__global__ __launch_bounds__(256) void ln_kernel(const float* __restrict__ x,
                                                 const float* __restrict__ w,
                                                 const float* __restrict__ b,
                                                 _Float16* __restrict__ oh) {
    int row = blockIdx.x;
    const float* xr = x + (size_t)row * DIM;
    int t = threadIdx.x;
    float v0 = xr[t], v1 = xr[t + 256], v2 = xr[t + 512];
    float s = v0 + v1 + v2;
    float sq = v0 * v0 + v1 * v1 + v2 * v2;
    __shared__ float red[8];
    int lane = t & 63, wid = t >> 6;
    #pragma unroll
    for (int off = 32; off; off >>= 1) {
        s  += __shfl_down(s, off);
        sq += __shfl_down(sq, off);
    }
    if (lane == 0) { red[wid] = s; red[4 + wid] = sq; }
    __syncthreads();
    if (t == 0) {
        float ts = red[0] + red[1] + red[2] + red[3];
        float tq = red[4] + red[5] + red[6] + red[7];
        float mu = ts * (1.0f / DIM);
        float var = tq * (1.0f / DIM) - mu * mu;
        red[0] = mu;
        red[1] = rsqrtf(var + 1e-6f);
    }
    __syncthreads();
    float mu = red[0], rstd = red[1];
    int sw = (row & 7) << 3;
    size_t ro = (size_t)row * DIM;
    #pragma unroll
    for (int e = 0; e < 3; ++e) {
        int c = t + e * 256;
        float v = (e == 0 ? v0 : (e == 1 ? v1 : v2));
        float val = (v - mu) * rstd * w[c] + b[c];
        oh[ro + (c ^ sw)] = (_Float16)val;
    }
}

// -------- weight convert: fp32 [K][N] -> fp16 [N][K], pre-swizzled --------
__global__ __launch_bounds__(256) void convert_wT(const float* __restrict__ src,
                                                  _Float16* __restrict__ dh,
                                                  int K, int N) {
    int n = blockIdx.x * 64 + (threadIdx.x & 63);
    int k0 = blockIdx.y * 32 + (threadIdx.x >> 6) * 8;
    f16x8 h8;
    #pragma unroll
    for (int j = 0; j < 8; ++j) h8[j] = (_Float16)src[(size_t)(k0 + j) * N + n];
    *(f16x8*)&dh[(size_t)n * K + (k0 ^ ((n & 7) << 3))] = h8;
}

// ---------------- fp16 MFMA GEMM: C = A @ W^T (+bias, +epi) ----------------
// A [Mpad][K], B [N][K] fp16, both pre-swizzled (k ^ ((row&7)<<3)).
// EPI: 1 = GELU -> fp16 plane, 2 = +resid fp32 out, 3 = QKV -> attention planes
template<int EPI>
__global__ __launch_bounds__(256) void gemm_mfma(
    const _Float16* __restrict__ A, const _Float16* __restrict__ B,
    const float* __restrict__ bias, const float* __restrict__ resid,
    float* __restrict__ C, _Float16* __restrict__ O,
    _Float16* __restrict__ pQ, _Float16* __restrict__ pK, _Float16* __restrict__ pVT,
    int M, int N, int K) {
    __shared__ _Float16 lds[2][128][64];  // A tile, B tile: 32 KiB
    int tid = threadIdx.x;
    int wid = tid >> 6, lane = tid & 63;
    int m0 = blockIdx.y * 128, n0 = blockIdx.x * 128;
    int wr = wid >> 1, wc = wid & 1;

    // wave wid stages 64 rows (8 issues x 1 KiB, linear LDS dest)
    const _Float16* src = (wid < 2) ? A : B;
    int srow0 = ((wid < 2) ? m0 : n0) + (wid & 1) * 64;
    _Float16* lbase = &lds[wid >> 1][(wid & 1) * 64][0];
    const _Float16* gbase = src + (size_t)(srow0 + (lane >> 3)) * K + (lane & 7) * 8;

    f32x4 acc[4][4];
    #pragma unroll
    for (int i = 0; i < 4; ++i)
        #pragma unroll
        for (int j = 0; j < 4; ++j) acc[i][j] = (f32x4)0.0f;

    for (int k0 = 0; k0 < K; k0 += 64) {
        #pragma unroll
        for (int i = 0; i < 8; ++i) {
            __builtin_amdgcn_global_load_lds(
                (const __attribute__((address_space(1))) void*)(gbase + (size_t)i * 8 * K + k0),
                (__attribute__((address_space(3))) void*)(lbase + i * 512),
                16, 0, 0);
        }
        __syncthreads();
        #pragma unroll
        for (int kk = 0; kk < 2; ++kk) {
            int so = (((kk * 4 + (lane >> 4)) ^ (lane & 7)) << 3);
            f16x8 af[4], bf[4];
            #pragma unroll
            for (int m = 0; m < 4; ++m)
                af[m] = *(const f16x8*)&lds[0][wr * 64 + m * 16 + (lane & 15)][so];
            #pragma unroll
            for (int n = 0; n < 4; ++n)
                bf[n] = *(const f16x8*)&lds[1][wc * 64 + n * 16 + (lane & 15)][so];
            #pragma unroll
            for (int m = 0; m < 4; ++m)
                #pragma unroll
                for (int n = 0; n < 4; ++n)
                    acc[m][n] = __builtin_amdgcn_mfma_f32_16x16x32_f16(af[m], bf[n], acc[m][n], 0, 0, 0);
        }
        __syncthreads();
    }

    // epilogue: C row = (lane>>4)*4 + reg, col = lane&15
    int rbase = m0 + wr * 64 + (lane >> 4) * 4;
    int cbase = n0 + wc * 64 + (lane & 15);
    #pragma unroll
    for (int mi = 0; mi < 4; ++mi) {
        #pragma unroll
        for (int ni = 0; ni < 4; ++ni) {
            int c = cbase + ni * 16;
            float bsv = bias[c];
            #pragma unroll
            for (int r4 = 0; r4 < 4; ++r4) {
                int r = rbase + mi * 16 + r4;
                if (r >= M) continue;
                float v = acc[mi][ni][r4] + bsv;
                if (EPI == 1) {
                    v = 0.5f * v * (1.0f + erff(v * 0.70710678118f));
                    O[(size_t)r * N + (c ^ ((r & 7) << 3))] = (_Float16)v;
                } else if (EPI == 2) {
                    v += resid[(size_t)r * N + c];
                    C[(size_t)r * N + c] = v;
                } else {  // EPI == 3: scatter to attention planes
                    int b_ = r / TT, t_ = r - b_ * TT;
                    int which = c / DIM, cc = c - which * DIM;
                    int head = cc >> 6, d = cc & 63;
                    size_t bh = (size_t)b_ * NH + head;
                    if (which == 0) {
                        pQ[(bh * TPAD + t_) * 64 + d] = (_Float16)(v * 0.125f);
                    } else if (which == 1) {
                        pK[(bh * TPAD + t_) * 64 + (d ^ ((t_ & 7) << 3))] = (_Float16)v;
                    } else {
                        pVT[(bh * 64 + d) * TPAD + ((t_ & ~63) | ((t_ & 63) ^ ((d & 7) << 3)))] = (_Float16)v;
                    }
                }
            }
        }
    }
}

// ---------------- fp16 MFMA flash attention: 4 waves x 16 q-rows, KBLK=64 ----------------
__global__ __launch_bounds__(256) void attn_mfma(
    const _Float16* __restrict__ Q, const _Float16* __restrict__ Kp,
    const _Float16* __restrict__ VT, _Float16* __restrict__ wa) {
    __shared__ _Float16 lds[12288];  // K [64][64] + VT [64][64] + P [4][16][64] = 24 KiB
    int tid = threadIdx.x, wid = tid >> 6, lane = tid & 63;
    int qt = blockIdx.x, h = blockIdx.y, b = blockIdx.z;
    size_t bh = (size_t)b * NH + h;

    // Q fragments in registers: A-frag row = lane&15, k-chunk = (lane>>4)*8
    int qrow = qt * 64 + wid * 16 + (lane & 15);
    const _Float16* qb = Q + (bh * TPAD + qrow) * 64 + (lane >> 4) * 8;
    f16x8 qf[2];
    qf[0] = *(const f16x8*)qb;
    qf[1] = *(const f16x8*)(qb + 32);

    f32x4 oacc[4];
    #pragma unroll
    for (int dt = 0; dt < 4; ++dt) oacc[dt] = (f32x4)0.0f;
    float m[4] = {-1e30f, -1e30f, -1e30f, -1e30f};
    float lsum[4] = {0.f, 0.f, 0.f, 0.f};

    _Float16* pbase = &lds[8192 + wid * 1024];

    for (int kt0 = 0; kt0 < TT; kt0 += 64) {
        // stage: waves 0-1 stage K tile, waves 2-3 stage VT tile (4 issues x 1 KiB each)
        _Float16* dst = &lds[(wid >> 1) * 4096 + (wid & 1) * 2048];
        const _Float16* gsrc;
        int istride;
        if (wid < 2) {
            gsrc = Kp + (bh * TPAD + kt0 + (wid & 1) * 32 + (lane >> 3)) * 64 + (lane & 7) * 8;
            istride = 8 * 64;
        } else {
            gsrc = VT + (bh * 64 + (wid & 1) * 32 + (lane >> 3)) * TPAD + kt0 + (lane & 7) * 8;
            istride = 8 * TPAD;
        }
        #pragma unroll
        for (int i = 0; i < 4; ++i) {
            __builtin_amdgcn_global_load_lds(
                (const __attribute__((address_space(1))) void*)(gsrc + (size_t)i * istride),
                (__attribute__((address_space(3))) void*)(dst + i * 512),
                16, 0, 0);
        }
        __syncthreads();

        // ---- QK^T: S[16q][64k] ----
        f32x4 sacc[4];
        #pragma unroll
        for (int kt = 0; kt < 4; ++kt) sacc[kt] = (f32x4)0.0f;
        #pragma unroll
        for (int dstep = 0; dstep < 2; ++dstep) {
            #pragma unroll
            for (int kt = 0; kt < 4; ++kt) {
                int krow = kt * 16 + (lane & 15);
                int ko = (((dstep * 4 + (lane >> 4)) ^ (krow & 7)) << 3);
                f16x8 kb = *(const f16x8*)&lds[krow * 64 + ko];
                sacc[kt] = __builtin_amdgcn_mfma_f32_16x16x32_f16(qf[dstep], kb, sacc[kt], 0, 0, 0);
            }
        }
        // mask pad k-cols
        #pragma unroll
        for (int kt = 0; kt < 4; ++kt) {
            int kcol = kt0 + kt * 16 + (lane & 15);
            if (kcol >= TT) {
                #pragma unroll
                for (int r = 0; r < 4; ++r) sacc[kt][r] = -1e30f;
            }
        }
        // ---- online softmax ----
        float mt[4];
        #pragma unroll
        for (int r = 0; r < 4; ++r)
            mt[r] = fmaxf(fmaxf(sacc[0][r], sacc[1][r]), fmaxf(sacc[2][r], sacc[3][r]));
        #pragma unroll
        for (int off = 1; off <= 8; off <<= 1) {
            #pragma unroll
            for (int r = 0; r < 4; ++r) mt[r] = fmaxf(mt[r], __shfl_xor(mt[r], off));
        }
        float corr[4];
        #pragma unroll
        for (int r = 0; r < 4; ++r) {
            float nm = fmaxf(m[r], mt[r]);
            corr[r] = __expf(m[r] - nm);
            m[r] = nm;
        }
        float rowsum[4] = {0.f, 0.f, 0.f, 0.f};
        #pragma unroll
        for (int kt = 0; kt < 4; ++kt) {
            #pragma unroll
            for (int r = 0; r < 4; ++r) {
                float p = __expf(sacc[kt][r] - m[r]);
                rowsum[r] += p;
                int q = (lane >> 4) * 4 + r;
                int kcol = kt * 16 + (lane & 15);
                pbase[q * 64 + (kcol ^ ((q & 7) << 3))] = (_Float16)p;
            }
        }
        #pragma unroll
        for (int off = 1; off <= 8; off <<= 1) {
            #pragma unroll
            for (int r = 0; r < 4; ++r) rowsum[r] += __shfl_xor(rowsum[r], off);
        }
        #pragma unroll
        for (int r = 0; r < 4; ++r) {
            lsum[r] = lsum[r] * corr[r] + rowsum[r];
            #pragma unroll
            for (int dt = 0; dt < 4; ++dt) oacc[dt][r] *= corr[r];
        }
        // ---- PV: O[16q][64d] += P * V ----
        #pragma unroll
        for (int kc = 0; kc < 2; ++kc) {
            int q = lane & 15;
            int pko = (((kc * 4 + (lane >> 4)) ^ (q & 7)) << 3);
            f16x8 pa = *(const f16x8*)&pbase[q * 64 + pko];
            #pragma unroll
            for (int dt = 0; dt < 4; ++dt) {
                int drow = dt * 16 + (lane & 15);
                int vo = (((kc * 4 + (lane >> 4)) ^ (drow & 7)) << 3);
                f16x8 vb = *(const f16x8*)&lds[4096 + drow * 64 + vo];
                oacc[dt] = __builtin_amdgcn_mfma_f32_16x16x32_f16(pa, vb, oacc[dt], 0, 0, 0);
            }
        }
        __syncthreads();
    }

    // ---- epilogue ----
    #pragma unroll
    for (int r = 0; r < 4; ++r) {
        int t = qt * 64 + wid * 16 + (lane >> 4) * 4 + r;
        if (t >= TT) continue;
        float inv = 1.0f / lsum[r];
        size_t row = (size_t)b * TT + t;
        int sw = (int)(row & 7) << 3;
        size_t ro = row * DIM;
        #pragma unroll
        for (int dt = 0; dt < 4; ++dt) {
            int c = h * 64 + dt * 16 + (lane & 15);
            wa[ro + (c ^ sw)] = (_Float16)(oacc[dt][r] * inv);
        }
    }
}

// --------------------------------------------------------------------------------
extern "C" void kernel_launch(void* const* d_in, const int* in_sizes, int n_in,
                              void* d_out, int out_size, void* d_ws, size_t ws_size,
                              hipStream_t stream) {
    const float* x      = (const float*)d_in[0];
    const float* ln1_w  = (const float*)d_in[1];
    const float* ln1_b  = (const float*)d_in[2];
    const float* qkv_w  = (const float*)d_in[3];
    const float* qkv_b  = (const float*)d_in[4];
    const float* proj_w = (const float*)d_in[5];
    const float* proj_b = (const float*)d_in[6];
    const float* ln2_w  = (const float*)d_in[7];
    const float* ln2_b  = (const float*)d_in[8];
    const float* fc1_w  = (const float*)d_in[9];
    const float* fc1_b  = (const float*)d_in[10];
    const float* fc2_w  = (const float*)d_in[11];
    const float* fc2_b  = (const float*)d_in[12];
    float* out = (float*)d_out;

    const size_t P768  = (size_t)MPAD * 768;
    const size_t P3072 = (size_t)MPAD * 3072;
    const size_t PQKV  = (size_t)BB * NH * TPAD * 64;
    char* wsb = (char*)d_ws;
    auto alloc = [&](size_t bytes) -> char* {
        char* p = wsb;
        wsb += (bytes + 255) & ~(size_t)255;
        return p;
    };
    _Float16* h_p   = (_Float16*)alloc(P768 * 2);
    _Float16* wa_p  = (_Float16*)alloc(P768 * 2);
    float* x1 = (float*)alloc((size_t)BT * 768 * 4);
    _Float16* qkvT = (_Float16*)alloc((size_t)2304 * 768 * 2);
    _Float16* projT = (_Float16*)alloc((size_t)768 * 768 * 2);
    _Float16* fc1T = (_Float16*)alloc((size_t)3072 * 768 * 2);
    _Float16* fc2T = (_Float16*)alloc((size_t)768 * 3072 * 2);
    // union region: {Q,K,VT planes: 3*PQKV} vs {hh: P3072} — disjoint lifetimes
    char* ubase = alloc(P3072 * 2 > 3 * PQKV * 2 ? P3072 * 2 : 3 * PQKV * 2);
    _Float16* pQ  = (_Float16*)ubase;
    _Float16* pK  = pQ + PQKV;
    _Float16* pVT = pK + PQKV;
    _Float16* hh  = (_Float16*)ubase;

    dim3 blk(256);
    int mt = (BT + 127) / 128;  // 73

    convert_wT<<<dim3(2304 / 64, 768 / 32), blk, 0, stream>>>(qkv_w, qkvT, 768, 2304);
    convert_wT<<<dim3(768 / 64, 768 / 32), blk, 0, stream>>>(proj_w, projT, 768, 768);
    convert_wT<<<dim3(3072 / 64, 768 / 32), blk, 0, stream>>>(fc1_w, fc1T, 768, 3072);
    convert_wT<<<dim3(768 / 64, 3072 / 32), blk, 0, stream>>>(fc2_w, fc2T, 3072, 768);

    // 1) h = LN1(x)
    ln_kernel<<<BT, blk, 0, stream>>>(x, ln1_w, ln1_b, h_p);
    // 2) qkv GEMM -> attention planes (Q scaled, K swizzled, V transposed)
    gemm_mfma<3><<<dim3(2304 / 128, mt), blk, 0, stream>>>(h_p, qkvT, qkv_b,
        nullptr, nullptr, nullptr, pQ, pK, pVT, BT, 2304, 768);
    // 3) wa = attention
    attn_mfma<<<dim3((TT + 63) / 64, NH, BB), blk, 0, stream>>>(pQ, pK, pVT, wa_p);
    // 4) x1 = x + wa @ proj_w + proj_b
    gemm_mfma<2><<<dim3(768 / 128, mt), blk, 0, stream>>>(wa_p, projT, proj_b,
        x, x1, nullptr, nullptr, nullptr, nullptr, BT, 768, 768);
    // 5) h = LN2(x1)
    ln_kernel<<<BT, blk, 0, stream>>>(x1, ln2_w, ln2_b, h_p);
    // 6) hh = gelu(h @ fc1_w + fc1_b)
    gemm_mfma<1><<<dim3(3072 / 128, mt), blk, 0, stream>>>(h_p, fc1T, fc1_b,
        nullptr, nullptr, hh, nullptr, nullptr, nullptr, BT, 3072, 768);
    // 7) out = x1 + hh @ fc2_w + fc2_b
    gemm_mfma<2><<<dim3(768 / 128, mt), blk, 0, stream>>>(hh, fc2T, fc2_b,
        x1, out, nullptr, nullptr, nullptr, nullptr, BT, 768, 3072);
}

// Round 9
// 490.000 us; speedup vs baseline: 5.6732x; 1.0693x over previous
//
#include <hip/hip_runtime.h>
#include <math.h>

#define DIM 768
#define NH 12
#define HIDDEN 3072
#define BB 16
#define TT 577
#define TPAD 640
#define BT (BB*TT)      // 9232
#define MPAD 9344       // 73*128

typedef _Float16 f16x8 __attribute__((ext_vector_type(8)));
typedef __attribute__((ext_vector_type(4))) float f32x4;

// ---------------- LayerNorm -> fp16 plane (pre-swizzled) ----------------
__global__ __launch_bounds__(256) void ln_kernel(const float* __restrict__ x,
                                                 const float* __restrict__ w,
                                                 const float* __restrict__ b,
                                                 _Float16* __restrict__ oh) {
    int row = blockIdx.x;
    const float* xr = x + (size_t)row * DIM;
    int t = threadIdx.x;
    float v0 = xr[t], v1 = xr[t + 256], v2 = xr[t + 512];
    float s = v0 + v1 + v2;
    float sq = v0 * v0 + v1 * v1 + v2 * v2;
    __shared__ float red[8];
    int lane = t & 63, wid = t >> 6;
    #pragma unroll
    for (int off = 32; off; off >>= 1) {
        s  += __shfl_down(s, off);
        sq += __shfl_down(sq, off);
    }
    if (lane == 0) { red[wid] = s; red[4 + wid] = sq; }
    __syncthreads();
    if (t == 0) {
        float ts = red[0] + red[1] + red[2] + red[3];
        float tq = red[4] + red[5] + red[6] + red[7];
        float mu = ts * (1.0f / DIM);
        float var = tq * (1.0f / DIM) - mu * mu;
        red[0] = mu;
        red[1] = rsqrtf(var + 1e-6f);
    }
    __syncthreads();
    float mu = red[0], rstd = red[1];
    int sw = (row & 7) << 3;
    size_t ro = (size_t)row * DIM;
    #pragma unroll
    for (int e = 0; e < 3; ++e) {
        int c = t + e * 256;
        float v = (e == 0 ? v0 : (e == 1 ? v1 : v2));
        float val = (v - mu) * rstd * w[c] + b[c];
        oh[ro + (c ^ sw)] = (_Float16)val;
    }
}

// -------- weight convert: fp32 [K][N] -> fp16 [N][K], pre-swizzled --------
__global__ __launch_bounds__(256) void convert_wT(const float* __restrict__ src,
                                                  _Float16* __restrict__ dh,
                                                  int K, int N) {
    int n = blockIdx.x * 64 + (threadIdx.x & 63);
    int k0 = blockIdx.y * 32 + (threadIdx.x >> 6) * 8;
    f16x8 h8;
    #pragma unroll
    for (int j = 0; j < 8; ++j) h8[j] = (_Float16)src[(size_t)(k0 + j) * N + n];
    *(f16x8*)&dh[(size_t)n * K + (k0 ^ ((n & 7) << 3))] = h8;
}

// ---------------- fp16 MFMA GEMM, double-buffered prefetch ----------------
// A [Mpad][K], B [N][K] fp16, both pre-swizzled (k ^ ((row&7)<<3)).
// EPI: 1 = GELU -> fp16 plane, 2 = +resid fp32 out, 3 = QKV -> attention planes
template<int EPI>
__global__ __launch_bounds__(256) void gemm_mfma(
    const _Float16* __restrict__ A, const _Float16* __restrict__ B,
    const float* __restrict__ bias, const float* __restrict__ resid,
    float* __restrict__ C, _Float16* __restrict__ O,
    _Float16* __restrict__ pQ, _Float16* __restrict__ pK, _Float16* __restrict__ pVT,
    int M, int N, int K) {
    __shared__ _Float16 lds[2][2][128][64];  // [dbuf][A/B][128][64] = 64 KiB
    int tid = threadIdx.x;
    int wid = tid >> 6, lane = tid & 63;
    int m0 = blockIdx.y * 128, n0 = blockIdx.x * 128;
    int wr = wid >> 1, wc = wid & 1;

    // wave wid stages 64 rows (8 issues x 1 KiB, linear LDS dest)
    const _Float16* src = (wid < 2) ? A : B;
    int srow0 = ((wid < 2) ? m0 : n0) + (wid & 1) * 64;
    const _Float16* gbase = src + (size_t)(srow0 + (lane >> 3)) * K + (lane & 7) * 8;
    _Float16* lb[2] = { &lds[0][wid >> 1][(wid & 1) * 64][0],
                        &lds[1][wid >> 1][(wid & 1) * 64][0] };

    f32x4 acc[4][4];
    #pragma unroll
    for (int i = 0; i < 4; ++i)
        #pragma unroll
        for (int j = 0; j < 4; ++j) acc[i][j] = (f32x4)0.0f;

    const int nk = K >> 6;
    // prologue: stage k-step 0 into buf 0
    #pragma unroll
    for (int i = 0; i < 8; ++i)
        __builtin_amdgcn_global_load_lds(
            (const __attribute__((address_space(1))) void*)(gbase + (size_t)i * 8 * K),
            (__attribute__((address_space(3))) void*)(lb[0] + i * 512), 16, 0, 0);
    __syncthreads();

    int cur = 0;
    for (int ks = 0; ks < nk; ++ks) {
        // prefetch next k-step into the other buffer (no wait — hides under MFMA)
        if (ks + 1 < nk) {
            int k0 = (ks + 1) << 6;
            #pragma unroll
            for (int i = 0; i < 8; ++i)
                __builtin_amdgcn_global_load_lds(
                    (const __attribute__((address_space(1))) void*)(gbase + (size_t)i * 8 * K + k0),
                    (__attribute__((address_space(3))) void*)(lb[cur ^ 1] + i * 512), 16, 0, 0);
        }
        // compute current buffer
        #pragma unroll
        for (int kk = 0; kk < 2; ++kk) {
            int so = (((kk * 4 + (lane >> 4)) ^ (lane & 7)) << 3);
            f16x8 af[4], bf[4];
            #pragma unroll
            for (int m = 0; m < 4; ++m)
                af[m] = *(const f16x8*)&lds[cur][0][wr * 64 + m * 16 + (lane & 15)][so];
            #pragma unroll
            for (int n = 0; n < 4; ++n)
                bf[n] = *(const f16x8*)&lds[cur][1][wc * 64 + n * 16 + (lane & 15)][so];
            #pragma unroll
            for (int m = 0; m < 4; ++m)
                #pragma unroll
                for (int n = 0; n < 4; ++n)
                    acc[m][n] = __builtin_amdgcn_mfma_f32_16x16x32_f16(af[m], bf[n], acc[m][n], 0, 0, 0);
        }
        __syncthreads();  // drains vm+lgkm: prefetch landed, buffer reads done
        cur ^= 1;
    }

    // epilogue: C row = (lane>>4)*4 + reg, col = lane&15
    int rbase = m0 + wr * 64 + (lane >> 4) * 4;
    int cbase = n0 + wc * 64 + (lane & 15);
    #pragma unroll
    for (int mi = 0; mi < 4; ++mi) {
        #pragma unroll
        for (int ni = 0; ni < 4; ++ni) {
            int c = cbase + ni * 16;
            float bsv = bias[c];
            #pragma unroll
            for (int r4 = 0; r4 < 4; ++r4) {
                int r = rbase + mi * 16 + r4;
                if (r >= M) continue;
                float v = acc[mi][ni][r4] + bsv;
                if (EPI == 1) {
                    // tanh-form GELU: v*sigmoid(1.5957691f*(v+0.044715f*v^3)); |err|<4e-4
                    v = v / (1.0f + __expf(-1.5957691216f * (v + 0.044715f * v * v * v)));
                    O[(size_t)r * N + (c ^ ((r & 7) << 3))] = (_Float16)v;
                } else if (EPI == 2) {
                    v += resid[(size_t)r * N + c];
                    C[(size_t)r * N + c] = v;
                } else {  // EPI == 3: scatter to attention planes
                    int b_ = r / TT, t_ = r - b_ * TT;
                    int which = c / DIM, cc = c - which * DIM;
                    int head = cc >> 6, d = cc & 63;
                    size_t bh = (size_t)b_ * NH + head;
                    if (which == 0) {
                        pQ[(bh * TPAD + t_) * 64 + d] = (_Float16)(v * 0.125f);
                    } else if (which == 1) {
                        pK[(bh * TPAD + t_) * 64 + (d ^ ((t_ & 7) << 3))] = (_Float16)v;
                    } else {
                        pVT[(bh * 64 + d) * TPAD + ((t_ & ~63) | ((t_ & 63) ^ ((d & 7) << 3)))] = (_Float16)v;
                    }
                }
            }
        }
    }
}

// ---------------- fp16 MFMA flash attention, double-buffered K/V ----------------
__global__ __launch_bounds__(256) void attn_mfma(
    const _Float16* __restrict__ Q, const _Float16* __restrict__ Kp,
    const _Float16* __restrict__ VT, _Float16* __restrict__ wa) {
    __shared__ _Float16 lds[20480];  // 2 x (K[64][64] + VT[64][64]) + P[4][16][64] = 40 KiB
    int tid = threadIdx.x, wid = tid >> 6, lane = tid & 63;
    int qt = blockIdx.x, h = blockIdx.y, b = blockIdx.z;
    size_t bh = (size_t)b * NH + h;

    // Q fragments in registers: A-frag row = lane&15, k-chunk = (lane>>4)*8
    int qrow = qt * 64 + wid * 16 + (lane & 15);
    const _Float16* qb = Q + (bh * TPAD + qrow) * 64 + (lane >> 4) * 8;
    f16x8 qf[2];
    qf[0] = *(const f16x8*)qb;
    qf[1] = *(const f16x8*)(qb + 32);

    f32x4 oacc[4];
    #pragma unroll
    for (int dt = 0; dt < 4; ++dt) oacc[dt] = (f32x4)0.0f;
    float m[4] = {-1e30f, -1e30f, -1e30f, -1e30f};
    float lsum[4] = {0.f, 0.f, 0.f, 0.f};

    _Float16* pbase = &lds[16384 + wid * 1024];
    // stage helper geometry: waves 0-1 stage K, waves 2-3 stage VT
    const _Float16* gK = Kp + (bh * TPAD + (wid & 1) * 32 + (lane >> 3)) * 64 + (lane & 7) * 8;
    const _Float16* gV = VT + (bh * 64 + (wid & 1) * 32 + (lane >> 3)) * TPAD + (lane & 7) * 8;
    int dstoff = (wid >> 1) * 4096 + (wid & 1) * 2048;

    // prologue: stage kt0=0 into buf 0
    #pragma unroll
    for (int i = 0; i < 4; ++i) {
        const _Float16* g = (wid < 2) ? (gK + (size_t)i * 8 * 64) : (gV + (size_t)i * 8 * TPAD);
        __builtin_amdgcn_global_load_lds(
            (const __attribute__((address_space(1))) void*)g,
            (__attribute__((address_space(3))) void*)(&lds[dstoff] + i * 512), 16, 0, 0);
    }
    __syncthreads();

    int cur = 0;
    for (int kt0 = 0; kt0 < TT; kt0 += 64) {
        // prefetch next K/V tile into other buffer
        if (kt0 + 64 < TT) {
            int nxt = kt0 + 64;
            #pragma unroll
            for (int i = 0; i < 4; ++i) {
                const _Float16* g = (wid < 2) ? (gK + (size_t)(nxt) * 64 + (size_t)i * 8 * 64)
                                              : (gV + nxt + (size_t)i * 8 * TPAD);
                __builtin_amdgcn_global_load_lds(
                    (const __attribute__((address_space(1))) void*)g,
                    (__attribute__((address_space(3))) void*)(&lds[(cur ^ 1) * 8192 + dstoff] + i * 512),
                    16, 0, 0);
            }
        }
        const _Float16* kbuf = &lds[cur * 8192];
        const _Float16* vbuf = &lds[cur * 8192 + 4096];

        // ---- QK^T: S[16q][64k] ----
        f32x4 sacc[4];
        #pragma unroll
        for (int kt = 0; kt < 4; ++kt) sacc[kt] = (f32x4)0.0f;
        #pragma unroll
        for (int dstep = 0; dstep < 2; ++dstep) {
            #pragma unroll
            for (int kt = 0; kt < 4; ++kt) {
                int krow = kt * 16 + (lane & 15);
                int ko = (((dstep * 4 + (lane >> 4)) ^ (krow & 7)) << 3);
                f16x8 kb = *(const f16x8*)&kbuf[krow * 64 + ko];
                sacc[kt] = __builtin_amdgcn_mfma_f32_16x16x32_f16(qf[dstep], kb, sacc[kt], 0, 0, 0);
            }
        }
        // mask pad k-cols
        #pragma unroll
        for (int kt = 0; kt < 4; ++kt) {
            int kcol = kt0 + kt * 16 + (lane & 15);
            if (kcol >= TT) {
                #pragma unroll
                for (int r = 0; r < 4; ++r) sacc[kt][r] = -1e30f;
            }
        }
        // ---- online softmax ----
        float mt[4];
        #pragma unroll
        for (int r = 0; r < 4; ++r)
            mt[r] = fmaxf(fmaxf(sacc[0][r], sacc[1][r]), fmaxf(sacc[2][r], sacc[3][r]));
        #pragma unroll
        for (int off = 1; off <= 8; off <<= 1) {
            #pragma unroll
            for (int r = 0; r < 4; ++r) mt[r] = fmaxf(mt[r], __shfl_xor(mt[r], off));
        }
        float corr[4];
        #pragma unroll
        for (int r = 0; r < 4; ++r) {
            float nm = fmaxf(m[r], mt[r]);
            corr[r] = __expf(m[r] - nm);
            m[r] = nm;
        }
        float rowsum[4] = {0.f, 0.f, 0.f, 0.f};
        #pragma unroll
        for (int kt = 0; kt < 4; ++kt) {
            #pragma unroll
            for (int r = 0; r < 4; ++r) {
                float p = __expf(sacc[kt][r] - m[r]);
                rowsum[r] += p;
                int q = (lane >> 4) * 4 + r;
                int kcol = kt * 16 + (lane & 15);
                pbase[q * 64 + (kcol ^ ((q & 7) << 3))] = (_Float16)p;
            }
        }
        #pragma unroll
        for (int off = 1; off <= 8; off <<= 1) {
            #pragma unroll
            for (int r = 0; r < 4; ++r) rowsum[r] += __shfl_xor(rowsum[r], off);
        }
        #pragma unroll
        for (int r = 0; r < 4; ++r) {
            lsum[r] = lsum[r] * corr[r] + rowsum[r];
            #pragma unroll
            for (int dt = 0; dt < 4; ++dt) oacc[dt][r] *= corr[r];
        }
        // ---- PV: O[16q][64d] += P * V ----
        #pragma unroll
        for (int kc = 0; kc < 2; ++kc) {
            int q = lane & 15;
            int pko = (((kc * 4 + (lane >> 4)) ^ (q & 7)) << 3);
            f16x8 pa = *(const f16x8*)&pbase[q * 64 + pko];
            #pragma unroll
            for (int dt = 0; dt < 4; ++dt) {
                int drow = dt * 16 + (lane & 15);
                int vo = (((kc * 4 + (lane >> 4)) ^ (drow & 7)) << 3);
                f16x8 vb = *(const f16x8*)&vbuf[drow * 64 + vo];
                oacc[dt] = __builtin_amdgcn_mfma_f32_16x16x32_f16(pa, vb, oacc[dt], 0, 0, 0);
            }
        }
        __syncthreads();
        cur ^= 1;
    }

    // ---- epilogue ----
    #pragma unroll
    for (int r = 0; r < 4; ++r) {
        int t = qt * 64 + wid * 16 + (lane >> 4) * 4 + r;
        if (t >= TT) continue;
        float inv = 1.0f / lsum[r];
        size_t row = (size_t)b * TT + t;
        int sw = (int)(row & 7) << 3;
        size_t ro = row * DIM;
        #pragma unroll
        for (int dt = 0; dt < 4; ++dt) {
            int c = h * 64 + dt * 16 + (lane & 15);
            wa[ro + (c ^ sw)] = (_Float16)(oacc[dt][r] * inv);
        }
    }
}

// --------------------------------------------------------------------------------
extern "C" void kernel_launch(void* const* d_in, const int* in_sizes, int n_in,
                              void* d_out, int out_size, void* d_ws, size_t ws_size,
                              hipStream_t stream) {
    const float* x      = (const float*)d_in[0];
    const float* ln1_w  = (const float*)d_in[1];
    const float* ln1_b  = (const float*)d_in[2];
    const float* qkv_w  = (const float*)d_in[3];
    const float* qkv_b  = (const float*)d_in[4];
    const float* proj_w = (const float*)d_in[5];
    const float* proj_b = (const float*)d_in[6];
    const float* ln2_w  = (const float*)d_in[7];
    const float* ln2_b  = (const float*)d_in[8];
    const float* fc1_w  = (const float*)d_in[9];
    const float* fc1_b  = (const float*)d_in[10];
    const float* fc2_w  = (const float*)d_in[11];
    const float* fc2_b  = (const float*)d_in[12];
    float* out = (float*)d_out;

    const size_t P768  = (size_t)MPAD * 768;
    const size_t P3072 = (size_t)MPAD * 3072;
    const size_t PQKV  = (size_t)BB * NH * TPAD * 64;
    char* wsb = (char*)d_ws;
    auto alloc = [&](size_t bytes) -> char* {
        char* p = wsb;
        wsb += (bytes + 255) & ~(size_t)255;
        return p;
    };
    _Float16* h_p   = (_Float16*)alloc(P768 * 2);
    _Float16* wa_p  = (_Float16*)alloc(P768 * 2);
    float* x1 = (float*)alloc((size_t)BT * 768 * 4);
    _Float16* qkvT = (_Float16*)alloc((size_t)2304 * 768 * 2);
    _Float16* projT = (_Float16*)alloc((size_t)768 * 768 * 2);
    _Float16* fc1T = (_Float16*)alloc((size_t)3072 * 768 * 2);
    _Float16* fc2T = (_Float16*)alloc((size_t)768 * 3072 * 2);
    char* ubase = alloc(P3072 * 2 > 3 * PQKV * 2 ? P3072 * 2 : 3 * PQKV * 2);
    _Float16* pQ  = (_Float16*)ubase;
    _Float16* pK  = pQ + PQKV;
    _Float16* pVT = pK + PQKV;
    _Float16* hh  = (_Float16*)ubase;

    dim3 blk(256);
    int mt = (BT + 127) / 128;  // 73

    convert_wT<<<dim3(2304 / 64, 768 / 32), blk, 0, stream>>>(qkv_w, qkvT, 768, 2304);
    convert_wT<<<dim3(768 / 64, 768 / 32), blk, 0, stream>>>(proj_w, projT, 768, 768);
    convert_wT<<<dim3(3072 / 64, 768 / 32), blk, 0, stream>>>(fc1_w, fc1T, 768, 3072);
    convert_wT<<<dim3(768 / 64, 3072 / 32), blk, 0, stream>>>(fc2_w, fc2T, 3072, 768);

    // 1) h = LN1(x)
    ln_kernel<<<BT, blk, 0, stream>>>(x, ln1_w, ln1_b, h_p);
    // 2) qkv GEMM -> attention planes (Q scaled, K swizzled, V transposed)
    gemm_mfma<3><<<dim3(2304 / 128, mt), blk, 0, stream>>>(h_p, qkvT, qkv_b,
        nullptr, nullptr, nullptr, pQ, pK, pVT, BT, 2304, 768);
    // 3) wa = attention
    attn_mfma<<<dim3((TT + 63) / 64, NH, BB), blk, 0, stream>>>(pQ, pK, pVT, wa_p);
    // 4) x1 = x + wa @ proj_w + proj_b
    gemm_mfma<2><<<dim3(768 / 128, mt), blk, 0, stream>>>(wa_p, projT, proj_b,
        x, x1, nullptr, nullptr, nullptr, nullptr, BT, 768, 768);
    // 5) h = LN2(x1)
    ln_kernel<<<BT, blk, 0, stream>>>(x1, ln2_w, ln2_b, h_p);
    // 6) hh = gelu(h @ fc1_w + fc1_b)
    gemm_mfma<1><<<dim3(3072 / 128, mt), blk, 0, stream>>>(h_p, fc1T, fc1_b,
        nullptr, nullptr, hh, nullptr, nullptr, nullptr, BT, 3072, 768);
    // 7) out = x1 + hh @ fc2_w + fc2_b
    gemm_mfma<2><<<dim3(768 / 128, mt), blk, 0, stream>>>(hh, fc2T, fc2_b,
        x1, out, nullptr, nullptr, nullptr, nullptr, BT, 768, 3072);
}